// Round 2
// baseline (404.986 us; speedup 1.0000x reference)
//
#include <hip/hip_runtime.h>
#include <hip/hip_bf16.h>
#include <cstdint>

// Problem constants
#define Ln 2048
#define Bn 64
#define Kd 256
#define Vd 256
#define Hn 8

using u32 = unsigned int;
using u16 = unsigned short;

__device__ __forceinline__ float bflo(u32 u) { return __uint_as_float(u << 16); }
__device__ __forceinline__ float bfhi(u32 u) { return __uint_as_float(u & 0xffff0000u); }
__device__ __forceinline__ float bf1(u16 s) { return __uint_as_float(((u32)s) << 16); }

// Device-side dtype sniff on `keys` (little-endian aware!):
// u16[2i] is the LOW mantissa half of float[i] for fp32 data -> exponent field
// uniform -> ~14% look like sane bf16. For genuine bf16 data u16[2i] is element
// 2i, a real N(0,1) value -> ~100% sane. Ballot across the wave separates.
__device__ __forceinline__ bool sniff_bf16(const void* keys) {
  const u16* q = (const u16*)keys;
  int lane = threadIdx.x & 63;
  u16 u = q[2 * (lane * 127)];  // EVEN u16 index
  u32 e = (u >> 7) & 0xff;
  bool sane = (u == 0) || (e >= 100 && e <= 134);
  return __popcll(__ballot(sane)) > 32;
}

// ---------------------------------------------------------------------------
// k_prep: rpe transpose [L][B]->[b][l]  +  q = query @ Wq + bq  (fp32 in ws)
// grid (4 chunks, 64 b), block 256
__global__ __launch_bounds__(256) void k_prep(const void* keys, const void* query,
                                              const void* rpe, const void* Wq,
                                              const void* bq, float* q_ws,
                                              float* rpe_t) {
  const bool bf = sniff_bf16(keys);
  const int t = threadIdx.x;
  const int chunk = blockIdx.x;  // 0..3
  const int b = blockIdx.y;      // 0..63

  // rpe transpose: coalesced writes, scattered (cached) reads
  int gt = (b * 4 + chunk) * 256 + t;  // 0..65535
#pragma unroll
  for (int j = 0; j < 2; j++) {
    int idx = j * 65536 + gt;  // = bb*2048 + l
    int bb = idx >> 11, l = idx & 2047;
    float v = bf ? bf1(((const u16*)rpe)[l * 64 + bb]) : ((const float*)rpe)[l * 64 + bb];
    rpe_t[idx] = v;
  }

  __shared__ float ql[256];
  ql[t] = bf ? bf1(((const u16*)query)[b * 256 + t]) : ((const float*)query)[b * 256 + t];
  __syncthreads();

  int c0 = chunk * 512 + 2 * t;  // two output columns per thread
  float a0, a1;
  if (bf) { a0 = bf1(((const u16*)bq)[c0]); a1 = bf1(((const u16*)bq)[c0 + 1]); }
  else    { a0 = ((const float*)bq)[c0];    a1 = ((const float*)bq)[c0 + 1]; }

  if (bf) {
    const u32* w = (const u32*)Wq;
#pragma unroll 4
    for (int k = 0; k < 256; k++) {
      u32 u = w[(size_t)k * 1024 + chunk * 256 + t];
      float qk = ql[k];
      a0 += qk * bflo(u); a1 += qk * bfhi(u);
    }
  } else {
    const float2* w = (const float2*)Wq;
#pragma unroll 4
    for (int k = 0; k < 256; k++) {
      float2 u = w[(size_t)k * 1024 + chunk * 256 + t];
      float qk = ql[k];
      a0 += qk * u.x; a1 += qk * u.y;
    }
  }
  q_ws[b * 2048 + c0] = a0;
  q_ws[b * 2048 + c0 + 1] = a1;
}

// ---------------------------------------------------------------------------
// k_scores: scores[(b*8+h)*L + l] = rpe[l,b] * <keys[l,b,:], q[b,h,:]>, l < steps[b]
// Unified dtype path: keys staged to LDS as fp32, 64-row tile, 2 K-half passes.
// grid (32 l-tiles of 64, 64 b), block 256
__global__ __launch_bounds__(256) void k_scores(const void* keys, const int* steps,
                                                const float* q_ws, const float* rpe_t,
                                                float* scores) {
  const int b = blockIdx.y, tile = blockIdx.x;
  const int lstart = tile * 64;
  const int stepb = steps[b];
  if (lstart >= stepb) return;  // dead tile: skip entirely
  const int lcnt = min(64, stepb - lstart);
  const bool bf = sniff_bf16(keys);
  const int t = threadIdx.x;
  const float* qb = q_ws + b * 2048;

  __shared__ float ks[64 * 132];     // 64 rows x 128 floats (+4 pad)
  __shared__ float part[4][64][9];   // k-quarter partial sums

  const int r = t & 63;
  const int kh = __builtin_amdgcn_readfirstlane(t >> 6);  // wave id = k-quarter of half
  float acc[8] = {0, 0, 0, 0, 0, 0, 0, 0};

  for (int khalf = 0; khalf < 2; khalf++) {
    // ---- stage 64 rows x 128 floats of this K-half into LDS (fp32) ----
    if (bf) {
      int r0 = t >> 4, c = t & 15;  // 16 uint4 (8 bf16 each) per row-half
#pragma unroll
      for (int rr = 0; rr < 4; rr++) {
        int row = r0 + rr * 16;
        const uint4* src = (const uint4*)((const u16*)keys +
            ((size_t)(lstart + row) * 64 + b) * 256 + khalf * 128);
        uint4 u = src[c];
        float* dst = &ks[row * 132 + c * 8];
        float4 lo, hi;
        lo.x = bflo(u.x); lo.y = bfhi(u.x); lo.z = bflo(u.y); lo.w = bfhi(u.y);
        hi.x = bflo(u.z); hi.y = bfhi(u.z); hi.z = bflo(u.w); hi.w = bfhi(u.w);
        *(float4*)dst = lo;
        *(float4*)(dst + 4) = hi;
      }
    } else {
      int r0 = t >> 5, c = t & 31;  // 32 float4 per row-half
#pragma unroll
      for (int rr = 0; rr < 8; rr++) {
        int row = r0 + rr * 8;
        const float4* src = (const float4*)((const float*)keys +
            ((size_t)(lstart + row) * 64 + b) * 256 + khalf * 128);
        *(float4*)&ks[row * 132 + c * 4] = src[c];
      }
    }
    __syncthreads();
    // ---- compute: lane owns row r, wave owns 32-float k-segment ----
    if (r < lcnt) {
#pragma unroll
      for (int i = 0; i < 8; i++) {
        float4 kv = *(const float4*)&ks[r * 132 + kh * 32 + 4 * i];
        int k0 = khalf * 128 + kh * 32 + 4 * i;  // wave-uniform -> s_load
#pragma unroll
        for (int h = 0; h < 8; h++) {
          float4 qv = *(const float4*)&qb[h * 256 + k0];
          acc[h] += kv.x * qv.x + kv.y * qv.y + kv.z * qv.z + kv.w * qv.w;
        }
      }
    }
    __syncthreads();
  }
  if (r < lcnt) {
#pragma unroll
    for (int h = 0; h < 8; h++) part[kh][r][h] = acc[h];
  }
  __syncthreads();
#pragma unroll
  for (int i = 0; i < 2; i++) {
    int idx = i * 256 + t;
    int h = idx >> 6, rr = idx & 63;
    if (rr < lcnt) {
      float s = part[0][rr][h] + part[1][rr][h] + part[2][rr][h] + part[3][rr][h];
      scores[(size_t)(b * 8 + h) * 2048 + lstart + rr] =
          s * rpe_t[b * 2048 + lstart + rr];
    }
  }
}

// ---------------------------------------------------------------------------
// k_softmax: per (b,h): m = max, w = exp(s-m) in place, zinv = 1/sum
// grid 512, block 256
__global__ __launch_bounds__(256) void k_softmax(const int* steps, float* scores,
                                                 float* zinv) {
  const int bh = blockIdx.x;
  const int n = steps[bh >> 3];
  float* sw = scores + (size_t)bh * 2048;
  const int t = threadIdx.x;
  __shared__ float red[4], red2[4];
  float m = -3.0e38f;
  for (int l = t; l < n; l += 256) m = fmaxf(m, sw[l]);
#pragma unroll
  for (int off = 32; off >= 1; off >>= 1) m = fmaxf(m, __shfl_xor(m, off, 64));
  if ((t & 63) == 0) red[t >> 6] = m;
  __syncthreads();
  m = fmaxf(fmaxf(red[0], red[1]), fmaxf(red[2], red[3]));
  float s = 0.f;
  for (int l = t; l < n; l += 256) {
    float e = __expf(sw[l] - m);
    sw[l] = e;
    s += e;
  }
#pragma unroll
  for (int off = 32; off >= 1; off >>= 1) s += __shfl_xor(s, off, 64);
  if ((t & 63) == 0) red2[t >> 6] = s;
  __syncthreads();
  if (t == 0) zinv[bh] = 1.0f / (red2[0] + red2[1] + red2[2] + red2[3]);
}

// ---------------------------------------------------------------------------
// k_read: read_part[tile][b][h][v] = sum_{l in tile, l<steps} w[l,b,h]*vals[l,b,v]
// grid (8 l-tiles of 256, 64 b), block 256 (128 v-pairs x 2 l-halves)
__global__ __launch_bounds__(256) void k_read(const void* keys, const void* vals,
                                              const int* steps, const float* w,
                                              float* read_part) {
  const int b = blockIdx.y, tile = blockIdx.x;
  const int lstart = tile * 256;
  const int stepb = steps[b];
  if (lstart >= stepb) return;
  const int lend = min(lstart + 256, stepb);
  const bool bf = sniff_bf16(keys);
  const int t = threadIdx.x;
  const int lh = __builtin_amdgcn_readfirstlane(t >> 7);  // l-half (wave-uniform)
  const int p = t & 127;                                  // v-pair index
  const float* wb = w + (size_t)b * 8 * 2048;
  float acc[16];
#pragma unroll
  for (int i = 0; i < 16; i++) acc[i] = 0.f;
  int l0 = lstart + lh * 128;
  int l1 = min(lend, l0 + 128);
  if (bf) {
    const u32* vu = (const u32*)vals;
    for (int l = l0; l < l1; l++) {
      float wv[8];
#pragma unroll
      for (int h = 0; h < 8; h++) wv[h] = wb[h * 2048 + l];  // uniform -> s_load
      u32 u = vu[((size_t)l * 64 + b) * 128 + p];
      float f0 = bflo(u), f1 = bfhi(u);
#pragma unroll
      for (int h = 0; h < 8; h++) {
        acc[2 * h] += wv[h] * f0;
        acc[2 * h + 1] += wv[h] * f1;
      }
    }
  } else {
    const float2* vf = (const float2*)vals;
    for (int l = l0; l < l1; l++) {
      float wv[8];
#pragma unroll
      for (int h = 0; h < 8; h++) wv[h] = wb[h * 2048 + l];
      float2 f = vf[((size_t)l * 64 + b) * 128 + p];
#pragma unroll
      for (int h = 0; h < 8; h++) {
        acc[2 * h] += wv[h] * f.x;
        acc[2 * h + 1] += wv[h] * f.y;
      }
    }
  }
  __shared__ float comb[128][17];
  if (lh == 1) {
#pragma unroll
    for (int i = 0; i < 16; i++) comb[p][i] = acc[i];
  }
  __syncthreads();
  if (lh == 0) {
#pragma unroll
    for (int i = 0; i < 16; i++) acc[i] += comb[p][i];
    float* rp = read_part + ((size_t)(tile * 64 + b)) * 2048;
#pragma unroll
    for (int h = 0; h < 8; h++) {
      float2 o;
      o.x = acc[2 * h];
      o.y = acc[2 * h + 1];
      *(float2*)&rp[h * 256 + 2 * p] = o;
    }
  }
}

// ---------------------------------------------------------------------------
// k_out1: per (h,b): rn[c] = (sum_tiles read_part)/Z; out_part = rn @ Wa-slice
// grid (8 h, 64 b), block 128 (2 v per thread)
__global__ __launch_bounds__(128) void k_out1(const void* keys, const void* Wa,
                                              const int* steps, const float* read_part,
                                              const float* zinv, float* out_part) {
  const int h = blockIdx.x, b = blockIdx.y;
  const bool bf = sniff_bf16(keys);
  const int t = threadIdx.x;  // 0..127
  const int nlive = (steps[b] + 255) >> 8;
  __shared__ float rn[256];
  const float zi = zinv[b * 8 + h];
  for (int i = t; i < 256; i += 128) {
    float s = 0.f;
    for (int tile = 0; tile < nlive; tile++)
      s += read_part[((size_t)(tile * 64 + b)) * 2048 + h * 256 + i];
    rn[i] = s * zi;
  }
  __syncthreads();
  float a0 = 0.f, a1 = 0.f;
  if (bf) {
    const u32* wa = (const u32*)Wa;
#pragma unroll 4
    for (int cc = 0; cc < 256; cc++) {
      u32 u = wa[(size_t)(h * 256 + cc) * 128 + t];
      float r = rn[cc];
      a0 += r * bflo(u);
      a1 += r * bfhi(u);
    }
  } else {
    const float2* wa = (const float2*)Wa;
#pragma unroll 4
    for (int cc = 0; cc < 256; cc++) {
      float2 u = wa[(size_t)(h * 256 + cc) * 128 + t];
      float r = rn[cc];
      a0 += r * u.x;
      a1 += r * u.y;
    }
  }
  float2 o;
  o.x = a0;
  o.y = a1;
  *(float2*)&out_part[(size_t)(h * 64 + b) * 256 + 2 * t] = o;
}

// ---------------------------------------------------------------------------
// k_out2: out[b,v] = sum_h out_part[h][b][v] + ba[v]   (output in sniffed dtype)
// grid 64, block 256
__global__ __launch_bounds__(256) void k_out2(const void* keys, const void* ba,
                                              const float* out_part, void* out) {
  const int b = blockIdx.x, t = threadIdx.x;
  const bool bf = sniff_bf16(keys);
  float s = bf ? bf1(((const u16*)ba)[t]) : ((const float*)ba)[t];
#pragma unroll
  for (int h = 0; h < 8; h++) s += out_part[(size_t)(h * 64 + b) * 256 + t];
  if (bf)
    ((__hip_bfloat16*)out)[b * 256 + t] = __float2bfloat16(s);
  else
    ((float*)out)[b * 256 + t] = s;
}

// ---------------------------------------------------------------------------
extern "C" void kernel_launch(void* const* d_in, const int* in_sizes, int n_in,
                              void* d_out, int out_size, void* d_ws, size_t ws_size,
                              hipStream_t stream) {
  (void)in_sizes; (void)n_in; (void)out_size; (void)ws_size;
  const void* query = d_in[0];
  const void* keys = d_in[1];
  const void* vals = d_in[2];
  const void* rpe = d_in[3];
  const void* Wq = d_in[4];
  const void* bq = d_in[5];
  const void* Wa = d_in[6];
  const void* ba = d_in[7];
  const int* steps = (const int*)d_in[8];

  float* ws = (float*)d_ws;
  float* q_ws = ws;                  // 131072 f
  float* rpe_t = ws + 131072;        // 131072 f
  float* scores = ws + 262144;       // 1048576 f (becomes w after softmax)
  float* zinv = ws + 1310720;        // 512 f
  float* read_part = ws + 1311232;   // 1048576 f
  float* out_part = ws + 2359808;    // 131072 f  (total ~9.5 MB)

  k_prep<<<dim3(4, 64), 256, 0, stream>>>(keys, query, rpe, Wq, bq, q_ws, rpe_t);
  k_scores<<<dim3(32, 64), 256, 0, stream>>>(keys, steps, q_ws, rpe_t, scores);
  k_softmax<<<512, 256, 0, stream>>>(steps, scores, zinv);
  k_read<<<dim3(8, 64), 256, 0, stream>>>(keys, vals, steps, scores, read_part);
  k_out1<<<dim3(8, 64), 128, 0, stream>>>(keys, Wa, steps, read_part, zinv, out_part);
  k_out2<<<64, 256, 0, stream>>>(keys, ba, out_part, d_out);
}

// Round 3
// 372.898 us; speedup vs baseline: 1.0861x; 1.0861x over previous
//
#include <hip/hip_runtime.h>
#include <hip/hip_bf16.h>
#include <cstdint>

// Problem constants
#define Ln 2048
#define Bn 64
#define Kd 256
#define Vd 256
#define Hn 8

using u32 = unsigned int;
using u16 = unsigned short;

__device__ __forceinline__ float bflo(u32 u) { return __uint_as_float(u << 16); }
__device__ __forceinline__ float bfhi(u32 u) { return __uint_as_float(u & 0xffff0000u); }
__device__ __forceinline__ float bf1(u16 s) { return __uint_as_float(((u32)s) << 16); }

// Device-side dtype sniff on `keys` (little-endian aware): u16[2i] is the LOW
// mantissa half of float[i] for fp32 data -> ~14% sane-bf16; for genuine bf16
// data it's a real N(0,1) value -> ~100% sane. (Round 1/2 verified: fp32.)
__device__ __forceinline__ bool sniff_bf16(const void* keys) {
  const u16* q = (const u16*)keys;
  int lane = threadIdx.x & 63;
  u16 u = q[2 * (lane * 127)];
  u32 e = (u >> 7) & 0xff;
  bool sane = (u == 0) || (e >= 100 && e <= 134);
  return __popcll(__ballot(sane)) > 32;
}

// ---------------------------------------------------------------------------
// k_prep: q = query @ Wq + bq  (fp32 in ws)   grid (4 chunks, 64 b), block 256
__global__ __launch_bounds__(256) void k_prep(const void* keys, const void* query,
                                              const void* Wq, const void* bq,
                                              float* q_ws) {
  const bool bf = sniff_bf16(keys);
  const int t = threadIdx.x;
  const int chunk = blockIdx.x;  // 0..3
  const int b = blockIdx.y;      // 0..63

  __shared__ float ql[256];
  ql[t] = bf ? bf1(((const u16*)query)[b * 256 + t]) : ((const float*)query)[b * 256 + t];
  __syncthreads();

  int c0 = chunk * 512 + 2 * t;  // two output columns per thread
  float a0, a1;
  if (bf) { a0 = bf1(((const u16*)bq)[c0]); a1 = bf1(((const u16*)bq)[c0 + 1]); }
  else    { a0 = ((const float*)bq)[c0];    a1 = ((const float*)bq)[c0 + 1]; }

  if (bf) {
    const u32* w = (const u32*)Wq;
#pragma unroll 4
    for (int k = 0; k < 256; k++) {
      u32 u = w[(size_t)k * 1024 + chunk * 256 + t];
      float qk = ql[k];
      a0 += qk * bflo(u); a1 += qk * bfhi(u);
    }
  } else {
    const float2* w = (const float2*)Wq;
#pragma unroll 4
    for (int k = 0; k < 256; k++) {
      float2 u = w[(size_t)k * 1024 + chunk * 256 + t];
      float qk = ql[k];
      a0 += qk * u.x; a1 += qk * u.y;
    }
  }
  q_ws[b * 2048 + c0] = a0;
  q_ws[b * 2048 + c0 + 1] = a1;
}

// ---------------------------------------------------------------------------
// k_fused: per (chunk of 128 l, b): scores (keys via LDS), partial softmax,
// weighted vals sum. Writes O_part[(c*64+b)][h*256+v] and mz_part[(c*64+b)*8+h].
// grid (16, 64), block 256.
__global__ __launch_bounds__(256) void k_fused(const void* keys, const void* vals,
                                               const void* rpe, const int* steps,
                                               const float* q_ws, float* O_part,
                                               float2* mz_part) {
  const int b = blockIdx.y, chunk = blockIdx.x;
  const int lstart = chunk * 128;
  const int stepb = steps[b];
  if (lstart >= stepb) return;  // dead chunk
  const int lcnt_chunk = min(128, stepb - lstart);
  const bool bf = sniff_bf16(keys);
  const int t = threadIdx.x;
  const float* qb = q_ws + b * 2048;  // wave-uniform base -> s_load for q reads

  union Shm {
    struct { float ks[64 * 132]; float part[4][64][9]; } sc;  // 43.0 KB
    float comb[128 * 20];                                     // 10 KB (read phase)
  };
  __shared__ Shm u;
  __shared__ __align__(16) float w_lds[128 * 12];  // scores -> weights, stride 12
  __shared__ float rpe_lds[128];

  // rpe staging (uncoalesced dwords, L2-shared across b)
  if (t < 128) {
    int l = lstart + t;
    rpe_lds[t] = bf ? bf1(((const u16*)rpe)[l * 64 + b]) : ((const float*)rpe)[l * 64 + b];
  }

  // ================= score phase: two 64-row sub-tiles =================
  for (int st = 0; st < 2; st++) {
    const int sbase = st * 64;
    if (lstart + sbase >= stepb) continue;  // block-uniform
    const int lcnt = min(64, stepb - lstart - sbase);
    const int r = t & 63;
    const int kh = __builtin_amdgcn_readfirstlane(t >> 6);  // wave = k-quarter
    float acc[8] = {0, 0, 0, 0, 0, 0, 0, 0};

    for (int khalf = 0; khalf < 2; khalf++) {
      __syncthreads();  // protect ks reuse across khalf/st
      if (bf) {
        int r0 = t >> 4, c = t & 15;
#pragma unroll
        for (int rr = 0; rr < 4; rr++) {
          int row = r0 + rr * 16;
          const uint4* src = (const uint4*)((const u16*)keys +
              ((size_t)(lstart + sbase + row) * 64 + b) * 256 + khalf * 128);
          uint4 uu = src[c];
          float* dst = &u.sc.ks[row * 132 + c * 8];
          float4 lo, hi;
          lo.x = bflo(uu.x); lo.y = bfhi(uu.x); lo.z = bflo(uu.y); lo.w = bfhi(uu.y);
          hi.x = bflo(uu.z); hi.y = bfhi(uu.z); hi.z = bflo(uu.w); hi.w = bfhi(uu.w);
          *(float4*)dst = lo;
          *(float4*)(dst + 4) = hi;
        }
      } else {
        int r0 = t >> 5, c = t & 31;
#pragma unroll
        for (int rr = 0; rr < 8; rr++) {
          int row = r0 + rr * 8;
          const float4* src = (const float4*)((const float*)keys +
              ((size_t)(lstart + sbase + row) * 64 + b) * 256 + khalf * 128);
          *(float4*)&u.sc.ks[row * 132 + c * 4] = src[c];
        }
      }
      __syncthreads();
      if (r < lcnt) {
#pragma unroll
        for (int i = 0; i < 8; i++) {
          float4 kv = *(const float4*)&u.sc.ks[r * 132 + kh * 32 + 4 * i];
          int k0 = khalf * 128 + kh * 32 + 4 * i;  // wave-uniform -> s_load
#pragma unroll
          for (int h = 0; h < 8; h++) {
            float4 qv = *(const float4*)&qb[h * 256 + k0];
            acc[h] += kv.x * qv.x + kv.y * qv.y + kv.z * qv.z + kv.w * qv.w;
          }
        }
      }
    }
    __syncthreads();
    if (r < lcnt) {
#pragma unroll
      for (int h = 0; h < 8; h++) u.sc.part[kh][r][h] = acc[h];
    }
    __syncthreads();
#pragma unroll
    for (int i = 0; i < 2; i++) {
      int idx = i * 256 + t;
      int h = idx >> 6, rr = idx & 63;
      if (rr < lcnt) {
        float s = u.sc.part[0][rr][h] + u.sc.part[1][rr][h] +
                  u.sc.part[2][rr][h] + u.sc.part[3][rr][h];
        w_lds[(sbase + rr) * 12 + h] = s * rpe_lds[sbase + rr];
      }
    }
  }
  __syncthreads();

  // ================= partial softmax: 32 threads per h =================
  __shared__ float2 mz_lds[8];
  {
    const int h = t >> 5, j = t & 31;
    float m = -3.0e38f;
#pragma unroll
    for (int i = 0; i < 4; i++) {
      int l = j + 32 * i;
      if (l < lcnt_chunk) m = fmaxf(m, w_lds[l * 12 + h]);
    }
#pragma unroll
    for (int off = 16; off >= 1; off >>= 1) m = fmaxf(m, __shfl_xor(m, off, 32));
    float zs = 0.f;
#pragma unroll
    for (int i = 0; i < 4; i++) {
      int l = j + 32 * i;
      float e = 0.f;
      if (l < lcnt_chunk) e = __expf(w_lds[l * 12 + h] - m);
      w_lds[l * 12 + h] = e;  // dead rows get 0
      zs += e;
    }
#pragma unroll
    for (int off = 16; off >= 1; off >>= 1) zs += __shfl_xor(zs, off, 32);
    if (j == 0) {
      float2 mz; mz.x = m; mz.y = zs;
      mz_lds[h] = mz;
    }
  }
  __syncthreads();
  if (t < 8) mz_part[((size_t)chunk * 64 + b) * 8 + t] = mz_lds[t];

  // ================= read phase: O_c[h][v] = sum_l w[l][h]*vals[l][v] ========
  const int vp = t & 127;                                  // v-pair
  const int lh = __builtin_amdgcn_readfirstlane(t >> 7);   // l-half (64 l each)
  float acc[8][2];
#pragma unroll
  for (int h = 0; h < 8; h++) { acc[h][0] = 0.f; acc[h][1] = 0.f; }

  if (bf) {
    const u32* vu = (const u32*)vals;
#pragma unroll 4
    for (int i = 0; i < 64; i++) {
      int l = lh * 64 + i;
      u32 uu = vu[((size_t)(lstart + l) * 64 + b) * 128 + vp];
      float f0 = bflo(uu), f1 = bfhi(uu);
      float4 w0 = *(const float4*)&w_lds[l * 12];
      float4 w1 = *(const float4*)&w_lds[l * 12 + 4];
      acc[0][0] += w0.x * f0; acc[0][1] += w0.x * f1;
      acc[1][0] += w0.y * f0; acc[1][1] += w0.y * f1;
      acc[2][0] += w0.z * f0; acc[2][1] += w0.z * f1;
      acc[3][0] += w0.w * f0; acc[3][1] += w0.w * f1;
      acc[4][0] += w1.x * f0; acc[4][1] += w1.x * f1;
      acc[5][0] += w1.y * f0; acc[5][1] += w1.y * f1;
      acc[6][0] += w1.z * f0; acc[6][1] += w1.z * f1;
      acc[7][0] += w1.w * f0; acc[7][1] += w1.w * f1;
    }
  } else {
    const float2* vf = (const float2*)vals;
#pragma unroll 4
    for (int i = 0; i < 64; i++) {
      int l = lh * 64 + i;
      float2 vv = vf[((size_t)(lstart + l) * 64 + b) * 128 + vp];
      float4 w0 = *(const float4*)&w_lds[l * 12];
      float4 w1 = *(const float4*)&w_lds[l * 12 + 4];
      acc[0][0] += w0.x * vv.x; acc[0][1] += w0.x * vv.y;
      acc[1][0] += w0.y * vv.x; acc[1][1] += w0.y * vv.y;
      acc[2][0] += w0.z * vv.x; acc[2][1] += w0.z * vv.y;
      acc[3][0] += w0.w * vv.x; acc[3][1] += w0.w * vv.y;
      acc[4][0] += w1.x * vv.x; acc[4][1] += w1.x * vv.y;
      acc[5][0] += w1.y * vv.x; acc[5][1] += w1.y * vv.y;
      acc[6][0] += w1.z * vv.x; acc[6][1] += w1.z * vv.y;
      acc[7][0] += w1.w * vv.x; acc[7][1] += w1.w * vv.y;
    }
  }
  __syncthreads();  // done with u.sc; reuse as comb
  if (lh == 1) {
#pragma unroll
    for (int h = 0; h < 8; h++) {
      u.comb[vp * 20 + 2 * h] = acc[h][0];
      u.comb[vp * 20 + 2 * h + 1] = acc[h][1];
    }
  }
  __syncthreads();
  if (lh == 0) {
    float* op = O_part + ((size_t)chunk * 64 + b) * 2048;
#pragma unroll
    for (int h = 0; h < 8; h++) {
      float2 o;
      o.x = acc[h][0] + u.comb[vp * 20 + 2 * h];
      o.y = acc[h][1] + u.comb[vp * 20 + 2 * h + 1];
      *(float2*)&op[h * 256 + 2 * vp] = o;
    }
  }
}

// ---------------------------------------------------------------------------
// k_out1: per (h,b): combine chunk partials -> rn[256]; out_part = rn @ Wa-slice
// grid (8 h, 64 b), block 128
__global__ __launch_bounds__(128) void k_out1(const void* keys, const void* Wa,
                                              const int* steps, const float* O_part,
                                              const float2* mz_part, float* out_part) {
  const int h = blockIdx.x, b = blockIdx.y;
  const bool bf = sniff_bf16(keys);
  const int t = threadIdx.x;  // 0..127
  const int nlive = (steps[b] + 127) >> 7;

  // global max & Z over live chunks (uniform scalar work)
  float M = -3.0e38f;
  for (int c = 0; c < nlive; c++) M = fmaxf(M, mz_part[((size_t)c * 64 + b) * 8 + h].x);
  float Z = 0.f;
  for (int c = 0; c < nlive; c++) {
    float2 mz = mz_part[((size_t)c * 64 + b) * 8 + h];
    Z += __expf(mz.x - M) * mz.y;
  }
  const float zi = 1.0f / Z;

  __shared__ float rn[256];
  for (int i = t; i < 256; i += 128) {
    float s = 0.f;
    for (int c = 0; c < nlive; c++) {
      float sc = __expf(mz_part[((size_t)c * 64 + b) * 8 + h].x - M);
      s += sc * O_part[((size_t)c * 64 + b) * 2048 + h * 256 + i];
    }
    rn[i] = s * zi;
  }
  __syncthreads();

  float a0 = 0.f, a1 = 0.f;
  if (bf) {
    const u32* wa = (const u32*)Wa;
#pragma unroll 4
    for (int cc = 0; cc < 256; cc++) {
      u32 u = wa[(size_t)(h * 256 + cc) * 128 + t];
      float r = rn[cc];
      a0 += r * bflo(u);
      a1 += r * bfhi(u);
    }
  } else {
    const float2* wa = (const float2*)Wa;
#pragma unroll 4
    for (int cc = 0; cc < 256; cc++) {
      float2 u = wa[(size_t)(h * 256 + cc) * 128 + t];
      float r = rn[cc];
      a0 += r * u.x;
      a1 += r * u.y;
    }
  }
  float2 o;
  o.x = a0;
  o.y = a1;
  *(float2*)&out_part[(size_t)(h * 64 + b) * 256 + 2 * t] = o;
}

// ---------------------------------------------------------------------------
// k_out2: out[b,v] = sum_h out_part[h][b][v] + ba[v]   (dtype by sniff)
// grid 64, block 256
__global__ __launch_bounds__(256) void k_out2(const void* keys, const void* ba,
                                              const float* out_part, void* out) {
  const int b = blockIdx.x, t = threadIdx.x;
  const bool bf = sniff_bf16(keys);
  float s = bf ? bf1(((const u16*)ba)[t]) : ((const float*)ba)[t];
#pragma unroll
  for (int h = 0; h < 8; h++) s += out_part[(size_t)(h * 64 + b) * 256 + t];
  if (bf)
    ((__hip_bfloat16*)out)[b * 256 + t] = __float2bfloat16(s);
  else
    ((float*)out)[b * 256 + t] = s;
}

// ---------------------------------------------------------------------------
extern "C" void kernel_launch(void* const* d_in, const int* in_sizes, int n_in,
                              void* d_out, int out_size, void* d_ws, size_t ws_size,
                              hipStream_t stream) {
  (void)in_sizes; (void)n_in; (void)out_size; (void)ws_size;
  const void* query = d_in[0];
  const void* keys = d_in[1];
  const void* vals = d_in[2];
  const void* rpe = d_in[3];
  const void* Wq = d_in[4];
  const void* bq = d_in[5];
  const void* Wa = d_in[6];
  const void* ba = d_in[7];
  const int* steps = (const int*)d_in[8];

  float* ws = (float*)d_ws;
  float* q_ws = ws;                      // 131072 f
  float* O_part = ws + 131072;           // 2097152 f (16 chunks x 64 b x 2048)
  float2* mz_part = (float2*)(ws + 2228224);  // 16384 f
  float* out_part = ws + 2244608;        // 131072 f  (total ~9.5 MB)

  k_prep<<<dim3(4, 64), 256, 0, stream>>>(keys, query, Wq, bq, q_ws);
  k_fused<<<dim3(16, 64), 256, 0, stream>>>(keys, vals, rpe, steps, q_ws, O_part, mz_part);
  k_out1<<<dim3(8, 64), 128, 0, stream>>>(keys, Wa, steps, O_part, mz_part, out_part);
  k_out2<<<64, 256, 0, stream>>>(keys, ba, out_part, d_out);
}

// Round 4
// 318.953 us; speedup vs baseline: 1.2697x; 1.1691x over previous
//
#include <hip/hip_runtime.h>
#include <hip/hip_bf16.h>
#include <cstdint>

// Problem constants
#define Ln 2048
#define Bn 64
#define Kd 256
#define Vd 256
#define Hn 8

using u32 = unsigned int;
using u16 = unsigned short;

__device__ __forceinline__ float bflo(u32 u) { return __uint_as_float(u << 16); }
__device__ __forceinline__ float bfhi(u32 u) { return __uint_as_float(u & 0xffff0000u); }
__device__ __forceinline__ float bf1(u16 s) { return __uint_as_float(((u32)s) << 16); }

// Device-side dtype sniff on `keys` (little-endian aware): u16[2i] is the LOW
// mantissa half of float[i] for fp32 data -> ~14% sane-bf16; for genuine bf16
// data it's a real N(0,1) value -> ~100% sane. (Rounds 1-3 verified: fp32.)
__device__ __forceinline__ bool sniff_bf16(const void* keys) {
  const u16* q = (const u16*)keys;
  int lane = threadIdx.x & 63;
  u16 u = q[2 * (lane * 127)];
  u32 e = (u >> 7) & 0xff;
  bool sane = (u == 0) || (e >= 100 && e <= 134);
  return __popcll(__ballot(sane)) > 32;
}

// ---------------------------------------------------------------------------
// k_prep: q = query @ Wq + bq  (fp32 in ws)   grid (4 chunks, 64 b), block 256
// Batched-16 loads: 16 outstanding vmem ops per round for latency hiding.
__global__ __launch_bounds__(256) void k_prep(const void* keys, const void* query,
                                              const void* Wq, const void* bq,
                                              float* q_ws) {
  const bool bf = sniff_bf16(keys);
  const int t = threadIdx.x;
  const int chunk = blockIdx.x;  // 0..3
  const int b = blockIdx.y;      // 0..63

  __shared__ float ql[256];
  ql[t] = bf ? bf1(((const u16*)query)[b * 256 + t]) : ((const float*)query)[b * 256 + t];
  __syncthreads();

  int c0 = chunk * 512 + 2 * t;  // two output columns per thread
  float a0, a1;
  if (bf) { a0 = bf1(((const u16*)bq)[c0]); a1 = bf1(((const u16*)bq)[c0 + 1]); }
  else    { a0 = ((const float*)bq)[c0];    a1 = ((const float*)bq)[c0 + 1]; }

  if (bf) {
    const u32* w = (const u32*)Wq + chunk * 256 + t;
    for (int k0 = 0; k0 < 256; k0 += 16) {
      u32 wv[16];
#pragma unroll
      for (int j = 0; j < 16; j++) wv[j] = w[(size_t)(k0 + j) * 1024];
#pragma unroll
      for (int j = 0; j < 16; j++) {
        float qk = ql[k0 + j];
        a0 += qk * bflo(wv[j]); a1 += qk * bfhi(wv[j]);
      }
    }
  } else {
    const float2* w = (const float2*)Wq + chunk * 256 + t;
    for (int k0 = 0; k0 < 256; k0 += 16) {
      float2 wv[16];
#pragma unroll
      for (int j = 0; j < 16; j++) wv[j] = w[(size_t)(k0 + j) * 1024];
#pragma unroll
      for (int j = 0; j < 16; j++) {
        float qk = ql[k0 + j];
        a0 += qk * wv[j].x; a1 += qk * wv[j].y;
      }
    }
  }
  q_ws[b * 2048 + c0] = a0;
  q_ws[b * 2048 + c0 + 1] = a1;
}

// ---------------------------------------------------------------------------
// k_fused: per (chunk of 128 l, b): scores (keys via LDS), partial softmax,
// weighted vals sum. Writes O_part[(c*64+b)][h*256+v] and mz_part[(c*64+b)*8+h].
// grid (16, 64), block 256.
__global__ __launch_bounds__(256) void k_fused(const void* keys, const void* vals,
                                               const void* rpe, const int* steps,
                                               const float* q_ws, float* O_part,
                                               float2* mz_part) {
  const int b = blockIdx.y, chunk = blockIdx.x;
  const int lstart = chunk * 128;
  const int stepb = steps[b];
  if (lstart >= stepb) return;  // dead chunk
  const int lcnt_chunk = min(128, stepb - lstart);
  const bool bf = sniff_bf16(keys);
  const int t = threadIdx.x;
  const float* qb = q_ws + b * 2048;  // wave-uniform base -> s_load for q reads

  union Shm {
    struct { float ks[64 * 132]; float part[4][64][9]; } sc;  // 43.0 KB
    float comb[128 * 20];                                     // 10 KB (read phase)
  };
  __shared__ Shm u;
  __shared__ __align__(16) float w_lds[128 * 12];  // scores -> weights, stride 12
  __shared__ float rpe_lds[128];

  // rpe staging (uncoalesced dwords, L2-shared across b)
  if (t < 128) {
    int l = lstart + t;
    rpe_lds[t] = bf ? bf1(((const u16*)rpe)[l * 64 + b]) : ((const float*)rpe)[l * 64 + b];
  }

  // ================= score phase: two 64-row sub-tiles =================
  for (int st = 0; st < 2; st++) {
    const int sbase = st * 64;
    if (lstart + sbase >= stepb) continue;  // block-uniform
    const int lcnt = min(64, stepb - lstart - sbase);
    const int r = t & 63;
    const int kh = __builtin_amdgcn_readfirstlane(t >> 6);  // wave = k-quarter
    float acc[8] = {0, 0, 0, 0, 0, 0, 0, 0};

    for (int khalf = 0; khalf < 2; khalf++) {
      __syncthreads();  // protect ks reuse across khalf/st
      if (bf) {
        int r0 = t >> 4, c = t & 15;
#pragma unroll
        for (int rr = 0; rr < 4; rr++) {
          int row = r0 + rr * 16;
          const uint4* src = (const uint4*)((const u16*)keys +
              ((size_t)(lstart + sbase + row) * 64 + b) * 256 + khalf * 128);
          uint4 uu = src[c];
          float* dst = &u.sc.ks[row * 132 + c * 8];
          float4 lo, hi;
          lo.x = bflo(uu.x); lo.y = bfhi(uu.x); lo.z = bflo(uu.y); lo.w = bfhi(uu.y);
          hi.x = bflo(uu.z); hi.y = bfhi(uu.z); hi.z = bflo(uu.w); hi.w = bfhi(uu.w);
          *(float4*)dst = lo;
          *(float4*)(dst + 4) = hi;
        }
      } else {
        int r0 = t >> 5, c = t & 31;
#pragma unroll
        for (int rr = 0; rr < 8; rr++) {
          int row = r0 + rr * 8;
          const float4* src = (const float4*)((const float*)keys +
              ((size_t)(lstart + sbase + row) * 64 + b) * 256 + khalf * 128);
          *(float4*)&u.sc.ks[row * 132 + c * 4] = src[c];
        }
      }
      __syncthreads();
      if (r < lcnt) {
#pragma unroll
        for (int i = 0; i < 8; i++) {
          float4 kv = *(const float4*)&u.sc.ks[r * 132 + kh * 32 + 4 * i];
          int k0 = khalf * 128 + kh * 32 + 4 * i;  // wave-uniform -> s_load
#pragma unroll
          for (int h = 0; h < 8; h++) {
            float4 qv = *(const float4*)&qb[h * 256 + k0];
            acc[h] += kv.x * qv.x + kv.y * qv.y + kv.z * qv.z + kv.w * qv.w;
          }
        }
      }
    }
    __syncthreads();
    if (r < lcnt) {
#pragma unroll
      for (int h = 0; h < 8; h++) u.sc.part[kh][r][h] = acc[h];
    }
    __syncthreads();
#pragma unroll
    for (int i = 0; i < 2; i++) {
      int idx = i * 256 + t;
      int h = idx >> 6, rr = idx & 63;
      if (rr < lcnt) {
        float s = u.sc.part[0][rr][h] + u.sc.part[1][rr][h] +
                  u.sc.part[2][rr][h] + u.sc.part[3][rr][h];
        w_lds[(sbase + rr) * 12 + h] = s * rpe_lds[sbase + rr];
      }
    }
  }
  __syncthreads();

  // ================= partial softmax: 32 threads per h =================
  __shared__ float2 mz_lds[8];
  {
    const int h = t >> 5, j = t & 31;
    float m = -3.0e38f;
#pragma unroll
    for (int i = 0; i < 4; i++) {
      int l = j + 32 * i;
      if (l < lcnt_chunk) m = fmaxf(m, w_lds[l * 12 + h]);
    }
#pragma unroll
    for (int off = 16; off >= 1; off >>= 1) m = fmaxf(m, __shfl_xor(m, off, 32));
    float zs = 0.f;
#pragma unroll
    for (int i = 0; i < 4; i++) {
      int l = j + 32 * i;
      float e = 0.f;
      if (l < lcnt_chunk) e = __expf(w_lds[l * 12 + h] - m);
      w_lds[l * 12 + h] = e;  // dead rows get 0
      zs += e;
    }
#pragma unroll
    for (int off = 16; off >= 1; off >>= 1) zs += __shfl_xor(zs, off, 32);
    if (j == 0) {
      float2 mz; mz.x = m; mz.y = zs;
      mz_lds[h] = mz;
    }
  }
  __syncthreads();
  if (t < 8) mz_part[((size_t)chunk * 64 + b) * 8 + t] = mz_lds[t];

  // ================= read phase: O_c[h][v] = sum_l w[l][h]*vals[l][v] ========
  // Batched-8 vals loads: 8 outstanding vmem per round, then consume from regs.
  const int vp = t & 127;                                  // v-pair
  const int lh = __builtin_amdgcn_readfirstlane(t >> 7);   // l-half (64 l each)
  float acc[8][2];
#pragma unroll
  for (int h = 0; h < 8; h++) { acc[h][0] = 0.f; acc[h][1] = 0.f; }

  if (bf) {
    const u32* vu = (const u32*)vals + ((size_t)(lstart + lh * 64) * 64 + b) * 128 + vp;
    for (int i0 = 0; i0 < 64; i0 += 8) {
      u32 uu[8];
#pragma unroll
      for (int j = 0; j < 8; j++) uu[j] = vu[(size_t)(i0 + j) * 8192];
#pragma unroll
      for (int j = 0; j < 8; j++) {
        int l = lh * 64 + i0 + j;
        float f0 = bflo(uu[j]), f1 = bfhi(uu[j]);
        float4 w0 = *(const float4*)&w_lds[l * 12];
        float4 w1 = *(const float4*)&w_lds[l * 12 + 4];
        acc[0][0] += w0.x * f0; acc[0][1] += w0.x * f1;
        acc[1][0] += w0.y * f0; acc[1][1] += w0.y * f1;
        acc[2][0] += w0.z * f0; acc[2][1] += w0.z * f1;
        acc[3][0] += w0.w * f0; acc[3][1] += w0.w * f1;
        acc[4][0] += w1.x * f0; acc[4][1] += w1.x * f1;
        acc[5][0] += w1.y * f0; acc[5][1] += w1.y * f1;
        acc[6][0] += w1.z * f0; acc[6][1] += w1.z * f1;
        acc[7][0] += w1.w * f0; acc[7][1] += w1.w * f1;
      }
    }
  } else {
    const float2* vf = (const float2*)vals + ((size_t)(lstart + lh * 64) * 64 + b) * 128 + vp;
    for (int i0 = 0; i0 < 64; i0 += 8) {
      float2 vv[8];
#pragma unroll
      for (int j = 0; j < 8; j++) vv[j] = vf[(size_t)(i0 + j) * 8192];
#pragma unroll
      for (int j = 0; j < 8; j++) {
        int l = lh * 64 + i0 + j;
        float4 w0 = *(const float4*)&w_lds[l * 12];
        float4 w1 = *(const float4*)&w_lds[l * 12 + 4];
        acc[0][0] += w0.x * vv[j].x; acc[0][1] += w0.x * vv[j].y;
        acc[1][0] += w0.y * vv[j].x; acc[1][1] += w0.y * vv[j].y;
        acc[2][0] += w0.z * vv[j].x; acc[2][1] += w0.z * vv[j].y;
        acc[3][0] += w0.w * vv[j].x; acc[3][1] += w0.w * vv[j].y;
        acc[4][0] += w1.x * vv[j].x; acc[4][1] += w1.x * vv[j].y;
        acc[5][0] += w1.y * vv[j].x; acc[5][1] += w1.y * vv[j].y;
        acc[6][0] += w1.z * vv[j].x; acc[6][1] += w1.z * vv[j].y;
        acc[7][0] += w1.w * vv[j].x; acc[7][1] += w1.w * vv[j].y;
      }
    }
  }
  __syncthreads();  // done with u.sc; reuse as comb
  if (lh == 1) {
#pragma unroll
    for (int h = 0; h < 8; h++) {
      u.comb[vp * 20 + 2 * h] = acc[h][0];
      u.comb[vp * 20 + 2 * h + 1] = acc[h][1];
    }
  }
  __syncthreads();
  if (lh == 0) {
    float* op = O_part + ((size_t)chunk * 64 + b) * 2048;
#pragma unroll
    for (int h = 0; h < 8; h++) {
      float2 o;
      o.x = acc[h][0] + u.comb[vp * 20 + 2 * h];
      o.y = acc[h][1] + u.comb[vp * 20 + 2 * h + 1];
      *(float2*)&op[h * 256 + 2 * vp] = o;
    }
  }
}

// ---------------------------------------------------------------------------
// k_out1: per (h,b): combine chunk partials -> rn[256]; out_part = rn @ Wa-slice
// grid (8 h, 64 b), block 256 (one output column each). Batched-16 loads.
__global__ __launch_bounds__(256) void k_out1(const void* keys, const void* Wa,
                                              const int* steps, const float* O_part,
                                              const float2* mz_part, float* out_part) {
  const int h = blockIdx.x, b = blockIdx.y;
  const bool bf = sniff_bf16(keys);
  const int t = threadIdx.x;  // 0..255 = output column
  const int nlive = (steps[b] + 127) >> 7;  // 1..16

  // chunk scale factors (uniform scalar work, all threads redundant)
  float2 mzv[16];
#pragma unroll
  for (int c = 0; c < 16; c++)
    mzv[c] = (c < nlive) ? mz_part[((size_t)c * 64 + b) * 8 + h] : make_float2(-3.0e38f, 0.f);
  float M = -3.0e38f;
#pragma unroll
  for (int c = 0; c < 16; c++) M = fmaxf(M, mzv[c].x);
  float sc[16];
  float Z = 0.f;
#pragma unroll
  for (int c = 0; c < 16; c++) {
    sc[c] = __expf(mzv[c].x - M);
    Z += sc[c] * mzv[c].y;
  }
  const float zi = 1.0f / Z;

  // combine O_part chunks (batched independent loads)
  __shared__ float rn[256];
  {
    const float* op = O_part + (size_t)b * 2048 + h * 256 + t;
    float ov[16];
#pragma unroll
    for (int c = 0; c < 16; c++) ov[c] = (c < nlive) ? op[(size_t)c * 131072] : 0.f;
    float s = 0.f;
#pragma unroll
    for (int c = 0; c < 16; c++) s += sc[c] * ov[c];
    rn[t] = s * zi;
  }
  __syncthreads();

  float a = 0.f;
  if (bf) {
    const u32* wa = (const u32*)Wa + (size_t)(h * 256) * 128 + (t >> 1);
    const bool hi = (t & 1);
    for (int c0 = 0; c0 < 256; c0 += 16) {
      u32 wv[16];
#pragma unroll
      for (int j = 0; j < 16; j++) wv[j] = wa[(size_t)(c0 + j) * 128];
#pragma unroll
      for (int j = 0; j < 16; j++)
        a += rn[c0 + j] * (hi ? bfhi(wv[j]) : bflo(wv[j]));
    }
  } else {
    const float* wa = (const float*)Wa + (size_t)(h * 256) * 256 + t;
    for (int c0 = 0; c0 < 256; c0 += 16) {
      float wv[16];
#pragma unroll
      for (int j = 0; j < 16; j++) wv[j] = wa[(size_t)(c0 + j) * 256];
#pragma unroll
      for (int j = 0; j < 16; j++) a += rn[c0 + j] * wv[j];
    }
  }
  out_part[(size_t)(h * 64 + b) * 256 + t] = a;
}

// ---------------------------------------------------------------------------
// k_out2: out[b,v] = sum_h out_part[h][b][v] + ba[v]   (dtype by sniff)
// grid 64, block 256
__global__ __launch_bounds__(256) void k_out2(const void* keys, const void* ba,
                                              const float* out_part, void* out) {
  const int b = blockIdx.x, t = threadIdx.x;
  const bool bf = sniff_bf16(keys);
  float s = bf ? bf1(((const u16*)ba)[t]) : ((const float*)ba)[t];
  float ov[8];
#pragma unroll
  for (int h = 0; h < 8; h++) ov[h] = out_part[(size_t)(h * 64 + b) * 256 + t];
#pragma unroll
  for (int h = 0; h < 8; h++) s += ov[h];
  if (bf)
    ((__hip_bfloat16*)out)[b * 256 + t] = __float2bfloat16(s);
  else
    ((float*)out)[b * 256 + t] = s;
}

// ---------------------------------------------------------------------------
extern "C" void kernel_launch(void* const* d_in, const int* in_sizes, int n_in,
                              void* d_out, int out_size, void* d_ws, size_t ws_size,
                              hipStream_t stream) {
  (void)in_sizes; (void)n_in; (void)out_size; (void)ws_size;
  const void* query = d_in[0];
  const void* keys = d_in[1];
  const void* vals = d_in[2];
  const void* rpe = d_in[3];
  const void* Wq = d_in[4];
  const void* bq = d_in[5];
  const void* Wa = d_in[6];
  const void* ba = d_in[7];
  const int* steps = (const int*)d_in[8];

  float* ws = (float*)d_ws;
  float* q_ws = ws;                      // 131072 f
  float* O_part = ws + 131072;           // 2097152 f (16 chunks x 64 b x 2048)
  float2* mz_part = (float2*)(ws + 2228224);  // 16384 f
  float* out_part = ws + 2244608;        // 131072 f  (total ~9.5 MB)

  k_prep<<<dim3(4, 64), 256, 0, stream>>>(keys, query, Wq, bq, q_ws);
  k_fused<<<dim3(16, 64), 256, 0, stream>>>(keys, vals, rpe, steps, q_ws, O_part, mz_part);
  k_out1<<<dim3(8, 64), 256, 0, stream>>>(keys, Wa, steps, O_part, mz_part, out_part);
  k_out2<<<64, 256, 0, stream>>>(keys, ba, out_part, d_out);
}